// Round 1
// 352.561 us; speedup vs baseline: 4.8702x; 4.8702x over previous
//
#include <hip/hip_runtime.h>
#include <stdint.h>

#define N_NODES 100000
#define CH 128
#define K_NEIGH 16
#define XS_STRIDE 68   // 64 + 4 pad: float4 rows, conflict-light

// ============================================================================
// Plan-B split (round 9):
//   fwd = W2 @ mean_k X[:,adj] == mean_k (W2 @ X)[:,adj]   (linearity)
// Kernel 1 (k_w2x_t): Y = W2 @ X, stored TRANSPOSED as Yt[N][C] in workspace.
// Kernel 2 (k_main):  Out[o][n] = (W1 @ X)[o][n] + mean_k Yt[adj[n][k]][o]
//                                + B1[o] + B2[o]
// Rationale (rocprof round 8): FETCH 5.4 GB vs 0.87 GB useful -- the [C][N]
// gather pulls one 64B line per 4B value (channel stride = 400 KB). Node-major
// Yt makes each neighbor a contiguous 512B read, fully coalesced.
// ============================================================================

// ---------------------------------------------------------------------------
// Kernel 1: Y^T = (W2 @ X)^T  -> Yt[N][CH]   (no bias; biases added in k_main)
// 64-node tile, 256 threads, same proven GEMM microkernel as the fused kernel.
// ---------------------------------------------------------------------------
__global__ __launch_bounds__(256, 2) void k_w2x_t(
    const float* __restrict__ X,    // [C][N] f32
    const float* __restrict__ W2,   // [o][c] f32
    float*       __restrict__ Yt)   // [N][C] f32 (workspace)
{
    __shared__ __align__(16) float Xs[CH * XS_STRIDE];

    const int t  = threadIdx.x;
    const int n0 = blockIdx.x * 64;
    const int V  = (N_NODES - n0 < 64) ? (N_NODES - n0) : 64;

    // stage X tile [c][n], guarded
    for (int it = 0; it < 32; ++it) {
        const int idx = t + it * 256;
        const int n = idx & 63, c = idx >> 6;
        Xs[c * XS_STRIDE + n] =
            (n < V) ? X[(size_t)c * N_NODES + n0 + n] : 0.0f;
    }
    __syncthreads();

    // GEMM: thread owns o = (t>>3)*4+i (i<4), n = (t&7)*8+j (j<8)
    const int ng = t & 7, og = t >> 3;
    float acc[4][8];
#pragma unroll
    for (int i = 0; i < 4; ++i)
#pragma unroll
        for (int j = 0; j < 8; ++j) acc[i][j] = 0.0f;

    const float* w2p = W2 + (og * 4) * CH;
    for (int c = 0; c < CH; ++c) {
        float xv[8], wv[4];
        *(float4*)&xv[0] = *(const float4*)&Xs[c * XS_STRIDE + ng * 8];
        *(float4*)&xv[4] = *(const float4*)&Xs[c * XS_STRIDE + ng * 8 + 4];
#pragma unroll
        for (int i = 0; i < 4; ++i) wv[i] = w2p[i * CH + c];
#pragma unroll
        for (int i = 0; i < 4; ++i)
#pragma unroll
            for (int j = 0; j < 8; ++j) acc[i][j] += wv[i] * xv[j];
    }

    // Direct transposed store: float4 across the i-dim (o contiguous).
    // Per wave instr: 8 node-rows x 128B contiguous segments, fully used.
#pragma unroll
    for (int j = 0; j < 8; ++j) {
        const int n = ng * 8 + j;
        if (n < V) {
            float4 v = make_float4(acc[0][j], acc[1][j], acc[2][j], acc[3][j]);
            *(float4*)&Yt[(size_t)(n0 + n) * CH + og * 4] = v;
        }
    }
}

// ---------------------------------------------------------------------------
// Kernel 2: Out = W1@X + gather-mean(Yt) + B1 + B2
// ---------------------------------------------------------------------------
__global__ __launch_bounds__(256, 2) void k_main(
    const float* __restrict__ X,    // [C][N] f32
    const int*   __restrict__ adj,  // [N][K] int32
    const float* __restrict__ W1,   // [o][c] f32
    const float* __restrict__ B1,
    const float* __restrict__ B2,
    const float* __restrict__ Yt,   // [N][C] f32
    float*       __restrict__ Out)  // [O][N] f32
{
    __shared__ __align__(16) float Xs[CH * XS_STRIDE];  // X tile [c][n]
    __shared__ __align__(16) float As[CH * XS_STRIDE];  // S = W2@agg tile [o][n]
    __shared__ int adjS[64 * K_NEIGH];

    const int t  = threadIdx.x;
    const int n0 = blockIdx.x * 64;
    const int V  = (N_NODES - n0 < 64) ? (N_NODES - n0) : 64;

    // ---- stage adj rows (guarded; pad rows gather node 0 harmlessly) ----
    {
        const int base  = n0 * K_NEIGH;
        const int valid = V * K_NEIGH;
        for (int idx = t; idx < 64 * K_NEIGH; idx += 256)
            adjS[idx] = (idx < valid) ? adj[base + idx] : 0;
    }

    // ---- stage X tile (f32, guarded) ----
    for (int it = 0; it < 32; ++it) {
        const int idx = t + it * 256;
        const int n = idx & 63, c = idx >> 6;
        Xs[c * XS_STRIDE + n] =
            (n < V) ? X[(size_t)c * N_NODES + n0 + n] : 0.0f;
    }
    __syncthreads();

    // ---- gather-sum from Yt: 32-lane group per node, lane = 4 channels ----
    // Group g handles nodes {g, 8+g, ..., 56+g}. Lane l loads float4 of
    // channels 4l..4l+3 of each neighbor: 512B contiguous per group per k,
    // fully coalesced. Two accumulator chains expose add ILP.
    {
        const int l4 = (t & 31) * 4;
        const int g  = t >> 5;
        for (int it = 0; it < 8; ++it) {
            const int n = it * 8 + g;
            int js[K_NEIGH];
#pragma unroll
            for (int k = 0; k < K_NEIGH; ++k) js[k] = adjS[n * K_NEIGH + k];
            float4 a0 = make_float4(0.f, 0.f, 0.f, 0.f);
            float4 a1 = make_float4(0.f, 0.f, 0.f, 0.f);
#pragma unroll
            for (int k = 0; k < K_NEIGH; k += 2) {
                const float4 v0 = *(const float4*)&Yt[(size_t)js[k]     * CH + l4];
                const float4 v1 = *(const float4*)&Yt[(size_t)js[k + 1] * CH + l4];
                a0.x += v0.x; a0.y += v0.y; a0.z += v0.z; a0.w += v0.w;
                a1.x += v1.x; a1.y += v1.y; a1.z += v1.z; a1.w += v1.w;
            }
            As[(l4 + 0) * XS_STRIDE + n] = (a0.x + a1.x) * 0.0625f;
            As[(l4 + 1) * XS_STRIDE + n] = (a0.y + a1.y) * 0.0625f;
            As[(l4 + 2) * XS_STRIDE + n] = (a0.z + a1.z) * 0.0625f;
            As[(l4 + 3) * XS_STRIDE + n] = (a0.w + a1.w) * 0.0625f;
        }
    }
    // NOTE: no barrier needed before the GEMM -- it only READS Xs (staged
    // before the barrier above) and does not touch As.

    // ---- single GEMM (W1 only): o = (t>>3)*4+i, n = (t&7)*8+j ----
    const int ng = t & 7, og = t >> 3;
    float acc[4][8];
#pragma unroll
    for (int i = 0; i < 4; ++i)
#pragma unroll
        for (int j = 0; j < 8; ++j) acc[i][j] = 0.0f;

    const float* w1p = W1 + (og * 4) * CH;
    for (int c = 0; c < CH; ++c) {
        float xv[8], w1v[4];
        *(float4*)&xv[0] = *(const float4*)&Xs[c * XS_STRIDE + ng * 8];
        *(float4*)&xv[4] = *(const float4*)&Xs[c * XS_STRIDE + ng * 8 + 4];
#pragma unroll
        for (int i = 0; i < 4; ++i) w1v[i] = w1p[i * CH + c];
#pragma unroll
        for (int i = 0; i < 4; ++i)
#pragma unroll
            for (int j = 0; j < 8; ++j) acc[i][j] += w1v[i] * xv[j];
    }

    // ---- pivot through LDS (reuse Xs), store o-major coalesced ----
    __syncthreads();   // all Xs reads done, all As writes done
    float* Zt = Xs;    // [128 o][stride 68]
#pragma unroll
    for (int i = 0; i < 4; ++i) {
        *(float4*)&Zt[(og * 4 + i) * XS_STRIDE + ng * 8]     = *(float4*)&acc[i][0];
        *(float4*)&Zt[(og * 4 + i) * XS_STRIDE + ng * 8 + 4] = *(float4*)&acc[i][4];
    }
    __syncthreads();
    for (int it = 0; it < 32; ++it) {
        const int idx = t + it * 256;
        const int n = idx & 63, o = idx >> 6;
        if (n < V) {
            Out[(size_t)o * N_NODES + n0 + n] =
                Zt[o * XS_STRIDE + n] + As[o * XS_STRIDE + n] + B1[o] + B2[o];
        }
    }
}

// ---------------------------------------------------------------------------
// Legacy fused kernel (round-8 audited) -- fallback if workspace too small.
// ---------------------------------------------------------------------------
__global__ __launch_bounds__(256, 2) void k_fused_legacy(
    const float* __restrict__ X,
    const int*   __restrict__ adj,
    const float* __restrict__ W1,
    const float* __restrict__ B1,
    const float* __restrict__ W2,
    const float* __restrict__ B2,
    float*       __restrict__ Out)
{
    __shared__ __align__(16) float Xs[CH * XS_STRIDE];
    __shared__ __align__(16) float As[CH * XS_STRIDE];
    __shared__ int adjS[64 * K_NEIGH];

    const int t  = threadIdx.x;
    const int n0 = blockIdx.x * 64;
    const int V  = (N_NODES - n0 < 64) ? (N_NODES - n0) : 64;

    {
        const int base  = n0 * K_NEIGH;
        const int valid = V * K_NEIGH;
        for (int idx = t; idx < 64 * K_NEIGH; idx += 256)
            adjS[idx] = (idx < valid) ? adj[base + idx] : 0;
    }
    for (int it = 0; it < 32; ++it) {
        const int idx = t + it * 256;
        const int n = idx & 63, c = idx >> 6;
        Xs[c * XS_STRIDE + n] =
            (n < V) ? X[(size_t)c * N_NODES + n0 + n] : 0.0f;
    }
    __syncthreads();

    {
        const int n_l = t & 63, q = t >> 6;
        int js[K_NEIGH];
#pragma unroll
        for (int k = 0; k < K_NEIGH; ++k) js[k] = adjS[n_l * K_NEIGH + k];
        if (n_l < V) {
            for (int cc = 0; cc < 32; ++cc) {
                const int c = q * 32 + cc;
                const float* xc = X + (size_t)c * N_NODES;
                float s = 0.0f;
#pragma unroll
                for (int k = 0; k < K_NEIGH; ++k) s += xc[js[k]];
                As[c * XS_STRIDE + n_l] = s * 0.0625f;
            }
        } else {
            for (int cc = 0; cc < 32; ++cc)
                As[(q * 32 + cc) * XS_STRIDE + n_l] = 0.0f;
        }
    }
    __syncthreads();

    const int ng = t & 7, og = t >> 3;
    float acc[4][8];
#pragma unroll
    for (int i = 0; i < 4; ++i)
#pragma unroll
        for (int j = 0; j < 8; ++j) acc[i][j] = 0.0f;

    const float* w1p = W1 + (og * 4) * CH;
    const float* w2p = W2 + (og * 4) * CH;
    for (int c = 0; c < CH; ++c) {
        float xv[8], av[8], w1v[4], w2v[4];
        *(float4*)&xv[0] = *(const float4*)&Xs[c * XS_STRIDE + ng * 8];
        *(float4*)&xv[4] = *(const float4*)&Xs[c * XS_STRIDE + ng * 8 + 4];
        *(float4*)&av[0] = *(const float4*)&As[c * XS_STRIDE + ng * 8];
        *(float4*)&av[4] = *(const float4*)&As[c * XS_STRIDE + ng * 8 + 4];
#pragma unroll
        for (int i = 0; i < 4; ++i) {
            w1v[i] = w1p[i * CH + c];
            w2v[i] = w2p[i * CH + c];
        }
#pragma unroll
        for (int i = 0; i < 4; ++i)
#pragma unroll
            for (int j = 0; j < 8; ++j)
                acc[i][j] += w1v[i] * xv[j] + w2v[i] * av[j];
    }

    __syncthreads();
    float* Zt = Xs;
#pragma unroll
    for (int i = 0; i < 4; ++i) {
        *(float4*)&Zt[(og * 4 + i) * XS_STRIDE + ng * 8]     = *(float4*)&acc[i][0];
        *(float4*)&Zt[(og * 4 + i) * XS_STRIDE + ng * 8 + 4] = *(float4*)&acc[i][4];
    }
    __syncthreads();
    for (int it = 0; it < 32; ++it) {
        const int idx = t + it * 256;
        const int n = idx & 63, o = idx >> 6;
        if (n < V) {
            Out[(size_t)o * N_NODES + n0 + n] =
                Zt[o * XS_STRIDE + n] + B1[o] + B2[o];
        }
    }
}

extern "C" void kernel_launch(void* const* d_in, const int* in_sizes, int n_in,
                              void* d_out, int out_size, void* d_ws, size_t ws_size,
                              hipStream_t stream) {
    const float* X   = (const float*)d_in[0];
    const int*   adj = (const int*)d_in[1];
    const float* W1  = (const float*)d_in[2];
    const float* B1  = (const float*)d_in[3];
    const float* W2  = (const float*)d_in[4];
    const float* B2  = (const float*)d_in[5];
    float* Out = (float*)d_out;

    const int nblocks = (N_NODES + 63) / 64;  // 1563
    const size_t yt_bytes = (size_t)N_NODES * CH * sizeof(float);  // 51.2 MB

    if (ws_size >= yt_bytes) {
        float* Yt = (float*)d_ws;
        k_w2x_t<<<nblocks, 256, 0, stream>>>(X, W2, Yt);
        k_main<<<nblocks, 256, 0, stream>>>(X, adj, W1, B1, B2, Yt, Out);
    } else {
        k_fused_legacy<<<nblocks, 256, 0, stream>>>(X, adj, W1, B1, W2, B2, Out);
    }
}

// Round 2
// 328.594 us; speedup vs baseline: 5.2254x; 1.0729x over previous
//
#include <hip/hip_runtime.h>
#include <stdint.h>

#define N_NODES 100000
#define CH 128
#define K_NEIGH 16
#define XS_STRIDE 68   // X tile stride: 64 + 4 pad
#define PS 132         // pivot buffer stride: 128 + 4 (node-major [n][o])

// Swizzled pivot index: key = ((n>>3)&3)<<3 flips o bits 3..4 only, so any
// 4-aligned float4 (o = 4l..4l+3) stays contiguous. Gather RMW: n const per
// 32-lane group -> contiguous 128-dword block -> conflict-free. Epilogue
// (lane=n, o fixed): banks (4n + o^key(n))%32 -> <=4-way.
#define PSWZ(n, o) ((n) * PS + ((o) ^ ((((n) >> 3) & 3) << 3)))

// ============================================================================
// Round 10: same Plan-B split (Yt = (W2@X)^T, then gather node-major), but:
//  * GEMM W loads vectorized to float4 (c chunked by 4): 4x fewer L2-latency
//    load instrs (round-1 evidence: GEMM phase ~150us in BOTH kernels).
//  * k_main LDS cut 73.7KB -> 38.9KB (As buffer eliminated; gather RMWs into
//    the swizzled acc-pivot buffer P aliased onto Xs) -> 4 blocks/CU.
//  * P swizzle kills the 6.4M-cycle 16-way LDS bank conflict.
// ============================================================================

// ---------------------------------------------------------------------------
// Kernel 1: Yt[N][C] = (W2 @ X)^T   (biases added in k_main)
// ---------------------------------------------------------------------------
__global__ __launch_bounds__(256, 4) void k_w2x_t(
    const float* __restrict__ X,    // [C][N] f32
    const float* __restrict__ W2,   // [o][c] f32
    float*       __restrict__ Yt)   // [N][C] f32 (workspace)
{
    __shared__ __align__(16) float Xs[CH * XS_STRIDE];  // 34.8 KB

    const int t  = threadIdx.x;
    const int n0 = blockIdx.x * 64;
    const int V  = (N_NODES - n0 < 64) ? (N_NODES - n0) : 64;

    for (int it = 0; it < 32; ++it) {
        const int idx = t + it * 256;
        const int n = idx & 63, c = idx >> 6;
        Xs[c * XS_STRIDE + n] =
            (n < V) ? X[(size_t)c * N_NODES + n0 + n] : 0.0f;
    }
    __syncthreads();

    const int ng = t & 7, og = t >> 3;
    float acc[4][8];
#pragma unroll
    for (int i = 0; i < 4; ++i)
#pragma unroll
        for (int j = 0; j < 8; ++j) acc[i][j] = 0.0f;

    const float* w2p = W2 + (og * 4) * CH;
    for (int c0 = 0; c0 < CH; c0 += 4) {
        float4 wv[4];
#pragma unroll
        for (int i = 0; i < 4; ++i)
            wv[i] = *(const float4*)&w2p[i * CH + c0];
#pragma unroll
        for (int cc = 0; cc < 4; ++cc) {
            float xv[8];
            *(float4*)&xv[0] = *(const float4*)&Xs[(c0 + cc) * XS_STRIDE + ng * 8];
            *(float4*)&xv[4] = *(const float4*)&Xs[(c0 + cc) * XS_STRIDE + ng * 8 + 4];
#pragma unroll
            for (int i = 0; i < 4; ++i) {
                const float w = ((const float*)&wv[i])[cc];
#pragma unroll
                for (int j = 0; j < 8; ++j) acc[i][j] += w * xv[j];
            }
        }
    }

    // Transposed store (proven round 1): per instr 8 nodes x 128B segments.
#pragma unroll
    for (int j = 0; j < 8; ++j) {
        const int n = ng * 8 + j;
        if (n < V) {
            float4 v = make_float4(acc[0][j], acc[1][j], acc[2][j], acc[3][j]);
            *(float4*)&Yt[(size_t)(n0 + n) * CH + og * 4] = v;
        }
    }
}

// ---------------------------------------------------------------------------
// Kernel 2: Out = W1@X + gather-mean(Yt) + B1 + B2
// LDS: Xs 34.8KB (aliased by pivot P after GEMM) + adjS 4KB = 38.9KB
//  -> 4 blocks/CU, 16 waves.
// ---------------------------------------------------------------------------
__global__ __launch_bounds__(256, 4) void k_main(
    const float* __restrict__ X,    // [C][N] f32
    const int*   __restrict__ adj,  // [N][K] int32
    const float* __restrict__ W1,   // [o][c] f32
    const float* __restrict__ B1,
    const float* __restrict__ B2,
    const float* __restrict__ Yt,   // [N][C] f32
    float*       __restrict__ Out)  // [O][N] f32
{
    __shared__ __align__(16) float Xs[CH * XS_STRIDE];  // 8704 f >= 64*132=8448
    __shared__ int adjS[64 * K_NEIGH];

    const int t  = threadIdx.x;
    const int n0 = blockIdx.x * 64;
    const int V  = (N_NODES - n0 < 64) ? (N_NODES - n0) : 64;

    // ---- stage adj + X tile ----
    {
        const int base  = n0 * K_NEIGH;
        const int valid = V * K_NEIGH;
        for (int idx = t; idx < 64 * K_NEIGH; idx += 256)
            adjS[idx] = (idx < valid) ? adj[base + idx] : 0;
    }
    for (int it = 0; it < 32; ++it) {
        const int idx = t + it * 256;
        const int n = idx & 63, c = idx >> 6;
        Xs[c * XS_STRIDE + n] =
            (n < V) ? X[(size_t)c * N_NODES + n0 + n] : 0.0f;
    }
    __syncthreads();

    // ---- GEMM (W1 only), float4-chunked W loads ----
    const int ng = t & 7, og = t >> 3;
    float acc[4][8];
#pragma unroll
    for (int i = 0; i < 4; ++i)
#pragma unroll
        for (int j = 0; j < 8; ++j) acc[i][j] = 0.0f;

    const float* w1p = W1 + (og * 4) * CH;
    for (int c0 = 0; c0 < CH; c0 += 4) {
        float4 wv[4];
#pragma unroll
        for (int i = 0; i < 4; ++i)
            wv[i] = *(const float4*)&w1p[i * CH + c0];
#pragma unroll
        for (int cc = 0; cc < 4; ++cc) {
            float xv[8];
            *(float4*)&xv[0] = *(const float4*)&Xs[(c0 + cc) * XS_STRIDE + ng * 8];
            *(float4*)&xv[4] = *(const float4*)&Xs[(c0 + cc) * XS_STRIDE + ng * 8 + 4];
#pragma unroll
            for (int i = 0; i < 4; ++i) {
                const float w = ((const float*)&wv[i])[cc];
#pragma unroll
                for (int j = 0; j < 8; ++j) acc[i][j] += w * xv[j];
            }
        }
    }

    // ---- pivot acc into swizzled node-major P (aliases Xs) ----
    __syncthreads();          // all Xs reads done
    float* P = Xs;            // [64 n][PS], swizzled
#pragma unroll
    for (int j = 0; j < 8; ++j) {
        const int n = ng * 8 + j;
        float4 v = make_float4(acc[0][j], acc[1][j], acc[2][j], acc[3][j]);
        *(float4*)&P[PSWZ(n, og * 4)] = v;
    }
    __syncthreads();

    // ---- gather-mean from Yt, RMW into P ----
    // 32-lane group per node; lane l owns channels 4l..4l+3 (float4).
    {
        const int l4 = (t & 31) * 4;
        const int g  = t >> 5;
        for (int it8 = 0; it8 < 8; ++it8) {
            const int n = it8 * 8 + g;
            int js[K_NEIGH];
#pragma unroll
            for (int k = 0; k < K_NEIGH; ++k) js[k] = adjS[n * K_NEIGH + k];
            float4 a0 = make_float4(0.f, 0.f, 0.f, 0.f);
            float4 a1 = make_float4(0.f, 0.f, 0.f, 0.f);
#pragma unroll
            for (int k = 0; k < K_NEIGH; k += 2) {
                const float4 v0 = *(const float4*)&Yt[(size_t)js[k]     * CH + l4];
                const float4 v1 = *(const float4*)&Yt[(size_t)js[k + 1] * CH + l4];
                a0.x += v0.x; a0.y += v0.y; a0.z += v0.z; a0.w += v0.w;
                a1.x += v1.x; a1.y += v1.y; a1.z += v1.z; a1.w += v1.w;
            }
            float4 cur = *(const float4*)&P[PSWZ(n, l4)];
            cur.x += (a0.x + a1.x) * 0.0625f;
            cur.y += (a0.y + a1.y) * 0.0625f;
            cur.z += (a0.z + a1.z) * 0.0625f;
            cur.w += (a0.w + a1.w) * 0.0625f;
            *(float4*)&P[PSWZ(n, l4)] = cur;
        }
    }
    __syncthreads();

    // ---- epilogue: coalesced o-major store ----
    for (int it = 0; it < 32; ++it) {
        const int idx = t + it * 256;
        const int n = idx & 63, o = idx >> 6;
        if (n < V) {
            Out[(size_t)o * N_NODES + n0 + n] =
                P[PSWZ(n, o)] + B1[o] + B2[o];
        }
    }
}

// ---------------------------------------------------------------------------
// Legacy fused kernel (round-8 audited) -- fallback if workspace too small.
// ---------------------------------------------------------------------------
__global__ __launch_bounds__(256, 2) void k_fused_legacy(
    const float* __restrict__ X,
    const int*   __restrict__ adj,
    const float* __restrict__ W1,
    const float* __restrict__ B1,
    const float* __restrict__ W2,
    const float* __restrict__ B2,
    float*       __restrict__ Out)
{
    __shared__ __align__(16) float Xs[CH * XS_STRIDE];
    __shared__ __align__(16) float As[CH * XS_STRIDE];
    __shared__ int adjS[64 * K_NEIGH];

    const int t  = threadIdx.x;
    const int n0 = blockIdx.x * 64;
    const int V  = (N_NODES - n0 < 64) ? (N_NODES - n0) : 64;

    {
        const int base  = n0 * K_NEIGH;
        const int valid = V * K_NEIGH;
        for (int idx = t; idx < 64 * K_NEIGH; idx += 256)
            adjS[idx] = (idx < valid) ? adj[base + idx] : 0;
    }
    for (int it = 0; it < 32; ++it) {
        const int idx = t + it * 256;
        const int n = idx & 63, c = idx >> 6;
        Xs[c * XS_STRIDE + n] =
            (n < V) ? X[(size_t)c * N_NODES + n0 + n] : 0.0f;
    }
    __syncthreads();

    {
        const int n_l = t & 63, q = t >> 6;
        int js[K_NEIGH];
#pragma unroll
        for (int k = 0; k < K_NEIGH; ++k) js[k] = adjS[n_l * K_NEIGH + k];
        if (n_l < V) {
            for (int cc = 0; cc < 32; ++cc) {
                const int c = q * 32 + cc;
                const float* xc = X + (size_t)c * N_NODES;
                float s = 0.0f;
#pragma unroll
                for (int k = 0; k < K_NEIGH; ++k) s += xc[js[k]];
                As[c * XS_STRIDE + n_l] = s * 0.0625f;
            }
        } else {
            for (int cc = 0; cc < 32; ++cc)
                As[(q * 32 + cc) * XS_STRIDE + n_l] = 0.0f;
        }
    }
    __syncthreads();

    const int ng = t & 7, og = t >> 3;
    float acc[4][8];
#pragma unroll
    for (int i = 0; i < 4; ++i)
#pragma unroll
        for (int j = 0; j < 8; ++j) acc[i][j] = 0.0f;

    const float* w1p = W1 + (og * 4) * CH;
    const float* w2p = W2 + (og * 4) * CH;
    for (int c = 0; c < CH; ++c) {
        float xv[8], av[8], w1v[4], w2v[4];
        *(float4*)&xv[0] = *(const float4*)&Xs[c * XS_STRIDE + ng * 8];
        *(float4*)&xv[4] = *(const float4*)&Xs[c * XS_STRIDE + ng * 8 + 4];
        *(float4*)&av[0] = *(const float4*)&As[c * XS_STRIDE + ng * 8];
        *(float4*)&av[4] = *(const float4*)&As[c * XS_STRIDE + ng * 8 + 4];
#pragma unroll
        for (int i = 0; i < 4; ++i) {
            w1v[i] = w1p[i * CH + c];
            w2v[i] = w2p[i * CH + c];
        }
#pragma unroll
        for (int i = 0; i < 4; ++i)
#pragma unroll
            for (int j = 0; j < 8; ++j)
                acc[i][j] += w1v[i] * xv[j] + w2v[i] * av[j];
    }

    __syncthreads();
    float* Zt = Xs;
#pragma unroll
    for (int i = 0; i < 4; ++i) {
        *(float4*)&Zt[(og * 4 + i) * XS_STRIDE + ng * 8]     = *(float4*)&acc[i][0];
        *(float4*)&Zt[(og * 4 + i) * XS_STRIDE + ng * 8 + 4] = *(float4*)&acc[i][4];
    }
    __syncthreads();
    for (int it = 0; it < 32; ++it) {
        const int idx = t + it * 256;
        const int n = idx & 63, o = idx >> 6;
        if (n < V) {
            Out[(size_t)o * N_NODES + n0 + n] =
                Zt[o * XS_STRIDE + n] + B1[o] + B2[o];
        }
    }
}

extern "C" void kernel_launch(void* const* d_in, const int* in_sizes, int n_in,
                              void* d_out, int out_size, void* d_ws, size_t ws_size,
                              hipStream_t stream) {
    const float* X   = (const float*)d_in[0];
    const int*   adj = (const int*)d_in[1];
    const float* W1  = (const float*)d_in[2];
    const float* B1  = (const float*)d_in[3];
    const float* W2  = (const float*)d_in[4];
    const float* B2  = (const float*)d_in[5];
    float* Out = (float*)d_out;

    const int nblocks = (N_NODES + 63) / 64;  // 1563
    const size_t yt_bytes = (size_t)N_NODES * CH * sizeof(float);  // 51.2 MB

    if (ws_size >= yt_bytes) {
        float* Yt = (float*)d_ws;
        k_w2x_t<<<nblocks, 256, 0, stream>>>(X, W2, Yt);
        k_main<<<nblocks, 256, 0, stream>>>(X, adj, W1, B1, B2, Yt, Out);
    } else {
        k_fused_legacy<<<nblocks, 256, 0, stream>>>(X, adj, W1, B1, W2, B2, Out);
    }
}

// Round 3
// 293.337 us; speedup vs baseline: 5.8535x; 1.1202x over previous
//
#include <hip/hip_runtime.h>
#include <stdint.h>

#define N_NODES 100000
#define CH 128
#define K_NEIGH 16
#define XS_STRIDE 68   // X tile stride: 64 + 4 pad (17 float4s -> 16B aligned rows)
#define PS 132         // pivot buffer stride: 128 + 4 (node-major [n][o])

// Swizzled pivot index: key = ((n>>3)&3)<<3 flips o bits 3..4 only, so any
// 4-aligned float4 (o = 4l..4l+3) stays contiguous. Gather RMW: n const per
// 32-lane group -> contiguous 128-dword block -> conflict-free. Epilogue
// (lane=n, o fixed): banks (4n + o^key(n))%32 -> <=4-way.
#define PSWZ(n, o) ((n) * PS + ((o) ^ ((((n) >> 3) & 3) << 3)))

// ============================================================================
// Round 11: latency attack (round-2 evidence: VALUBusy 25%, HBM 34%, nothing
// saturated; k_w2x_t stuck at ~160us == pure W-load stall in the GEMM loop,
// VGPR_Count=64 proves no prefetch distance).
//  * GEMM: software-pipelined W prefetch (peeled last chunk).
//  * Gather: 2-node unroll, 32 loads in flight, 4 accumulation chains.
//  * float4/int4 staging loads; float4 epilogue stores along n.
// ============================================================================

// ---------------------------------------------------------------------------
// Kernel 1: Yt[N][C] = (W2 @ X)^T   (biases added in k_main)
// ---------------------------------------------------------------------------
__global__ __launch_bounds__(256, 4) void k_w2x_t(
    const float* __restrict__ X,    // [C][N] f32
    const float* __restrict__ W2,   // [o][c] f32
    float*       __restrict__ Yt)   // [N][C] f32 (workspace)
{
    __shared__ __align__(16) float Xs[CH * XS_STRIDE];  // 34.8 KB

    const int t  = threadIdx.x;
    const int n0 = blockIdx.x * 64;
    const int V  = (N_NODES - n0 < 64) ? (N_NODES - n0) : 64;

    // stage X tile as float4: 2048 float4s, 8 per thread. V%4==0 always.
    for (int it = 0; it < 8; ++it) {
        const int idx = t + it * 256;          // 0..2047
        const int nq = idx & 15, c = idx >> 4; // nq: float4 col, c: channel
        float4 v = make_float4(0.f, 0.f, 0.f, 0.f);
        if (nq * 4 < V)
            v = *(const float4*)&X[(size_t)c * N_NODES + n0 + nq * 4];
        *(float4*)&Xs[c * XS_STRIDE + nq * 4] = v;
    }
    __syncthreads();

    const int ng = t & 7, og = t >> 3;
    float acc[4][8];
#pragma unroll
    for (int i = 0; i < 4; ++i)
#pragma unroll
        for (int j = 0; j < 8; ++j) acc[i][j] = 0.0f;

    const float* w2p = W2 + (og * 4) * CH;

    // software-pipelined W: prefetch chunk c0+4 while FMAing chunk c0
    float4 wv[4], wn[4];
#pragma unroll
    for (int i = 0; i < 4; ++i) wv[i] = *(const float4*)&w2p[i * CH];

    for (int c0 = 0; c0 < CH - 4; c0 += 4) {
#pragma unroll
        for (int i = 0; i < 4; ++i)
            wn[i] = *(const float4*)&w2p[i * CH + c0 + 4];
#pragma unroll
        for (int cc = 0; cc < 4; ++cc) {
            const float* xrow = &Xs[(c0 + cc) * XS_STRIDE + ng * 8];
            float xv[8];
            *(float4*)&xv[0] = *(const float4*)&xrow[0];
            *(float4*)&xv[4] = *(const float4*)&xrow[4];
#pragma unroll
            for (int i = 0; i < 4; ++i) {
                const float w = ((const float*)&wv[i])[cc];
#pragma unroll
                for (int j = 0; j < 8; ++j) acc[i][j] += w * xv[j];
            }
        }
#pragma unroll
        for (int i = 0; i < 4; ++i) wv[i] = wn[i];
    }
    {   // peeled last chunk (c0 = CH-4)
        const int c0 = CH - 4;
#pragma unroll
        for (int cc = 0; cc < 4; ++cc) {
            const float* xrow = &Xs[(c0 + cc) * XS_STRIDE + ng * 8];
            float xv[8];
            *(float4*)&xv[0] = *(const float4*)&xrow[0];
            *(float4*)&xv[4] = *(const float4*)&xrow[4];
#pragma unroll
            for (int i = 0; i < 4; ++i) {
                const float w = ((const float*)&wv[i])[cc];
#pragma unroll
                for (int j = 0; j < 8; ++j) acc[i][j] += w * xv[j];
            }
        }
    }

    // Transposed store: per instr 8 nodes x 128B contiguous segments.
#pragma unroll
    for (int j = 0; j < 8; ++j) {
        const int n = ng * 8 + j;
        if (n < V) {
            float4 v = make_float4(acc[0][j], acc[1][j], acc[2][j], acc[3][j]);
            *(float4*)&Yt[(size_t)(n0 + n) * CH + og * 4] = v;
        }
    }
}

// ---------------------------------------------------------------------------
// Kernel 2: Out = W1@X + gather-mean(Yt) + B1 + B2
// LDS: Xs 34.8KB (aliased by pivot P after GEMM) + adjS 4KB -> 4 blocks/CU.
// ---------------------------------------------------------------------------
__global__ __launch_bounds__(256, 4) void k_main(
    const float* __restrict__ X,    // [C][N] f32
    const int*   __restrict__ adj,  // [N][K] int32
    const float* __restrict__ W1,   // [o][c] f32
    const float* __restrict__ B1,
    const float* __restrict__ B2,
    const float* __restrict__ Yt,   // [N][C] f32
    float*       __restrict__ Out)  // [O][N] f32
{
    __shared__ __align__(16) float Xs[CH * XS_STRIDE];  // 8704 f >= 64*132=8448
    __shared__ __align__(16) int adjS[64 * K_NEIGH];    // 1024 ints

    const int t  = threadIdx.x;
    const int n0 = blockIdx.x * 64;
    const int V  = (N_NODES - n0 < 64) ? (N_NODES - n0) : 64;

    // ---- stage adj as int4 (1024 ints = 256 int4s, 1 per thread) ----
    {
        const int base  = n0 * K_NEIGH;   // int index, 4-aligned
        const int valid = V * K_NEIGH;    // V%32==0 -> valid%4==0
        int4 a = make_int4(0, 0, 0, 0);
        if (t * 4 < valid)
            a = *(const int4*)&adj[base + t * 4];
        *(int4*)&adjS[t * 4] = a;
    }
    // ---- stage X tile as float4 ----
    for (int it = 0; it < 8; ++it) {
        const int idx = t + it * 256;
        const int nq = idx & 15, c = idx >> 4;
        float4 v = make_float4(0.f, 0.f, 0.f, 0.f);
        if (nq * 4 < V)
            v = *(const float4*)&X[(size_t)c * N_NODES + n0 + nq * 4];
        *(float4*)&Xs[c * XS_STRIDE + nq * 4] = v;
    }
    __syncthreads();

    // ---- GEMM (W1), software-pipelined W prefetch ----
    const int ng = t & 7, og = t >> 3;
    float acc[4][8];
#pragma unroll
    for (int i = 0; i < 4; ++i)
#pragma unroll
        for (int j = 0; j < 8; ++j) acc[i][j] = 0.0f;

    const float* w1p = W1 + (og * 4) * CH;
    float4 wv[4], wn[4];
#pragma unroll
    for (int i = 0; i < 4; ++i) wv[i] = *(const float4*)&w1p[i * CH];

    for (int c0 = 0; c0 < CH - 4; c0 += 4) {
#pragma unroll
        for (int i = 0; i < 4; ++i)
            wn[i] = *(const float4*)&w1p[i * CH + c0 + 4];
#pragma unroll
        for (int cc = 0; cc < 4; ++cc) {
            const float* xrow = &Xs[(c0 + cc) * XS_STRIDE + ng * 8];
            float xv[8];
            *(float4*)&xv[0] = *(const float4*)&xrow[0];
            *(float4*)&xv[4] = *(const float4*)&xrow[4];
#pragma unroll
            for (int i = 0; i < 4; ++i) {
                const float w = ((const float*)&wv[i])[cc];
#pragma unroll
                for (int j = 0; j < 8; ++j) acc[i][j] += w * xv[j];
            }
        }
#pragma unroll
        for (int i = 0; i < 4; ++i) wv[i] = wn[i];
    }
    {   // peeled last chunk
        const int c0 = CH - 4;
#pragma unroll
        for (int cc = 0; cc < 4; ++cc) {
            const float* xrow = &Xs[(c0 + cc) * XS_STRIDE + ng * 8];
            float xv[8];
            *(float4*)&xv[0] = *(const float4*)&xrow[0];
            *(float4*)&xv[4] = *(const float4*)&xrow[4];
#pragma unroll
            for (int i = 0; i < 4; ++i) {
                const float w = ((const float*)&wv[i])[cc];
#pragma unroll
                for (int j = 0; j < 8; ++j) acc[i][j] += w * xv[j];
            }
        }
    }

    // ---- pivot acc into swizzled node-major P (aliases Xs) ----
    __syncthreads();          // all Xs reads done
    float* P = Xs;            // [64 n][PS], swizzled
#pragma unroll
    for (int j = 0; j < 8; ++j) {
        const int n = ng * 8 + j;
        float4 v = make_float4(acc[0][j], acc[1][j], acc[2][j], acc[3][j]);
        *(float4*)&P[PSWZ(n, og * 4)] = v;
    }
    __syncthreads();

    // ---- gather-mean from Yt, RMW into P; 2 nodes in flight ----
    // 32-lane group per node; lane l owns channels 4l..4l+3 (float4).
    {
        const int l4 = (t & 31) * 4;
        const int g  = t >> 5;
        for (int itp = 0; itp < 4; ++itp) {
            const int nA = itp * 16 + g;
            const int nB = nA + 8;
            int jA[K_NEIGH], jB[K_NEIGH];
#pragma unroll
            for (int k = 0; k < K_NEIGH; ++k) jA[k] = adjS[nA * K_NEIGH + k];
#pragma unroll
            for (int k = 0; k < K_NEIGH; ++k) jB[k] = adjS[nB * K_NEIGH + k];
            float4 aA0 = make_float4(0.f, 0.f, 0.f, 0.f);
            float4 aA1 = make_float4(0.f, 0.f, 0.f, 0.f);
            float4 aB0 = make_float4(0.f, 0.f, 0.f, 0.f);
            float4 aB1 = make_float4(0.f, 0.f, 0.f, 0.f);
#pragma unroll
            for (int k = 0; k < K_NEIGH; k += 2) {
                const float4 vA0 = *(const float4*)&Yt[(size_t)jA[k]     * CH + l4];
                const float4 vA1 = *(const float4*)&Yt[(size_t)jA[k + 1] * CH + l4];
                const float4 vB0 = *(const float4*)&Yt[(size_t)jB[k]     * CH + l4];
                const float4 vB1 = *(const float4*)&Yt[(size_t)jB[k + 1] * CH + l4];
                aA0.x += vA0.x; aA0.y += vA0.y; aA0.z += vA0.z; aA0.w += vA0.w;
                aA1.x += vA1.x; aA1.y += vA1.y; aA1.z += vA1.z; aA1.w += vA1.w;
                aB0.x += vB0.x; aB0.y += vB0.y; aB0.z += vB0.z; aB0.w += vB0.w;
                aB1.x += vB1.x; aB1.y += vB1.y; aB1.z += vB1.z; aB1.w += vB1.w;
            }
            float4 cA = *(const float4*)&P[PSWZ(nA, l4)];
            cA.x += (aA0.x + aA1.x) * 0.0625f;
            cA.y += (aA0.y + aA1.y) * 0.0625f;
            cA.z += (aA0.z + aA1.z) * 0.0625f;
            cA.w += (aA0.w + aA1.w) * 0.0625f;
            *(float4*)&P[PSWZ(nA, l4)] = cA;
            float4 cB = *(const float4*)&P[PSWZ(nB, l4)];
            cB.x += (aB0.x + aB1.x) * 0.0625f;
            cB.y += (aB0.y + aB1.y) * 0.0625f;
            cB.z += (aB0.z + aB1.z) * 0.0625f;
            cB.w += (aB0.w + aB1.w) * 0.0625f;
            *(float4*)&P[PSWZ(nB, l4)] = cB;
        }
    }
    __syncthreads();

    // ---- epilogue: float4-per-thread o-major stores (1KB/wave-instr) ----
    for (int it = 0; it < 8; ++it) {
        const int idx = t + it * 256;          // 0..2047
        const int nq = idx & 15, o = idx >> 4; // o: 0..127
        if (nq * 4 < V) {
            const float bb = B1[o] + B2[o];
            float4 v;
            v.x = P[PSWZ(nq * 4 + 0, o)] + bb;
            v.y = P[PSWZ(nq * 4 + 1, o)] + bb;
            v.z = P[PSWZ(nq * 4 + 2, o)] + bb;
            v.w = P[PSWZ(nq * 4 + 3, o)] + bb;
            *(float4*)&Out[(size_t)o * N_NODES + n0 + nq * 4] = v;
        }
    }
}

// ---------------------------------------------------------------------------
// Legacy fused kernel (round-8 audited) -- fallback if workspace too small.
// ---------------------------------------------------------------------------
__global__ __launch_bounds__(256, 2) void k_fused_legacy(
    const float* __restrict__ X,
    const int*   __restrict__ adj,
    const float* __restrict__ W1,
    const float* __restrict__ B1,
    const float* __restrict__ W2,
    const float* __restrict__ B2,
    float*       __restrict__ Out)
{
    __shared__ __align__(16) float Xs[CH * XS_STRIDE];
    __shared__ __align__(16) float As[CH * XS_STRIDE];
    __shared__ int adjS[64 * K_NEIGH];

    const int t  = threadIdx.x;
    const int n0 = blockIdx.x * 64;
    const int V  = (N_NODES - n0 < 64) ? (N_NODES - n0) : 64;

    {
        const int base  = n0 * K_NEIGH;
        const int valid = V * K_NEIGH;
        for (int idx = t; idx < 64 * K_NEIGH; idx += 256)
            adjS[idx] = (idx < valid) ? adj[base + idx] : 0;
    }
    for (int it = 0; it < 32; ++it) {
        const int idx = t + it * 256;
        const int n = idx & 63, c = idx >> 6;
        Xs[c * XS_STRIDE + n] =
            (n < V) ? X[(size_t)c * N_NODES + n0 + n] : 0.0f;
    }
    __syncthreads();

    {
        const int n_l = t & 63, q = t >> 6;
        int js[K_NEIGH];
#pragma unroll
        for (int k = 0; k < K_NEIGH; ++k) js[k] = adjS[n_l * K_NEIGH + k];
        if (n_l < V) {
            for (int cc = 0; cc < 32; ++cc) {
                const int c = q * 32 + cc;
                const float* xc = X + (size_t)c * N_NODES;
                float s = 0.0f;
#pragma unroll
                for (int k = 0; k < K_NEIGH; ++k) s += xc[js[k]];
                As[c * XS_STRIDE + n_l] = s * 0.0625f;
            }
        } else {
            for (int cc = 0; cc < 32; ++cc)
                As[(q * 32 + cc) * XS_STRIDE + n_l] = 0.0f;
        }
    }
    __syncthreads();

    const int ng = t & 7, og = t >> 3;
    float acc[4][8];
#pragma unroll
    for (int i = 0; i < 4; ++i)
#pragma unroll
        for (int j = 0; j < 8; ++j) acc[i][j] = 0.0f;

    const float* w1p = W1 + (og * 4) * CH;
    const float* w2p = W2 + (og * 4) * CH;
    for (int c = 0; c < CH; ++c) {
        float xv[8], av[8], w1v[4], w2v[4];
        *(float4*)&xv[0] = *(const float4*)&Xs[c * XS_STRIDE + ng * 8];
        *(float4*)&xv[4] = *(const float4*)&Xs[c * XS_STRIDE + ng * 8 + 4];
        *(float4*)&av[0] = *(const float4*)&As[c * XS_STRIDE + ng * 8];
        *(float4*)&av[4] = *(const float4*)&As[c * XS_STRIDE + ng * 8 + 4];
#pragma unroll
        for (int i = 0; i < 4; ++i) {
            w1v[i] = w1p[i * CH + c];
            w2v[i] = w2p[i * CH + c];
        }
#pragma unroll
        for (int i = 0; i < 4; ++i)
#pragma unroll
            for (int j = 0; j < 8; ++j)
                acc[i][j] += w1v[i] * xv[j] + w2v[i] * av[j];
    }

    __syncthreads();
    float* Zt = Xs;
#pragma unroll
    for (int i = 0; i < 4; ++i) {
        *(float4*)&Zt[(og * 4 + i) * XS_STRIDE + ng * 8]     = *(float4*)&acc[i][0];
        *(float4*)&Zt[(og * 4 + i) * XS_STRIDE + ng * 8 + 4] = *(float4*)&acc[i][4];
    }
    __syncthreads();
    for (int it = 0; it < 32; ++it) {
        const int idx = t + it * 256;
        const int n = idx & 63, o = idx >> 6;
        if (n < V) {
            Out[(size_t)o * N_NODES + n0 + n] =
                Zt[o * XS_STRIDE + n] + B1[o] + B2[o];
        }
    }
}

extern "C" void kernel_launch(void* const* d_in, const int* in_sizes, int n_in,
                              void* d_out, int out_size, void* d_ws, size_t ws_size,
                              hipStream_t stream) {
    const float* X   = (const float*)d_in[0];
    const int*   adj = (const int*)d_in[1];
    const float* W1  = (const float*)d_in[2];
    const float* B1  = (const float*)d_in[3];
    const float* W2  = (const float*)d_in[4];
    const float* B2  = (const float*)d_in[5];
    float* Out = (float*)d_out;

    const int nblocks = (N_NODES + 63) / 64;  // 1563
    const size_t yt_bytes = (size_t)N_NODES * CH * sizeof(float);  // 51.2 MB

    if (ws_size >= yt_bytes) {
        float* Yt = (float*)d_ws;
        k_w2x_t<<<nblocks, 256, 0, stream>>>(X, W2, Yt);
        k_main<<<nblocks, 256, 0, stream>>>(X, adj, W1, B1, B2, Yt, Out);
    } else {
        k_fused_legacy<<<nblocks, 256, 0, stream>>>(X, adj, W1, B1, W2, B2, Out);
    }
}